// Round 2
// baseline (689.613 us; speedup 1.0000x reference)
//
#include <hip/hip_runtime.h>

// COO SpMM: out[b,d] = sum_{e: row[e]==d} vals[e] * x[b, col[e]] + bias[d]
// B=64 (one wave), NUM_SRC=NUM_DST=100000, NNZ=3.2M, all fp32.
//
// R2 plan: no CSR build (R1 scatter had 200MB partial-line write
// amplification, 245us). Direct atomic SpMM: one wave per edge-chunk,
// lane b does unsafeAtomicAdd(accT[row*64+b], vals*xT[col*64+b]).
// The 64-lane atomic covers 4 full 64B lines -> no write amplification,
// accT (25.6MB) is L2/L3 resident.

// ---------- transpose x (B=64, nsrc) -> xT (nsrc, 64) ----------
__global__ __launch_bounds__(1024) void transpose_x_kernel(
    const float* __restrict__ x, float* __restrict__ xT, int nsrc) {
  __shared__ float tile[64][65];
  int s0 = blockIdx.x * 64;
  int tx = threadIdx.x;  // 0..63
  int ty = threadIdx.y;  // 0..15
#pragma unroll
  for (int i = 0; i < 4; ++i) {
    int b = ty + i * 16;
    int s = s0 + tx;
    tile[tx][b] = (s < nsrc) ? x[(size_t)b * nsrc + s] : 0.f;
  }
  __syncthreads();
#pragma unroll
  for (int i = 0; i < 4; ++i) {
    int sl = ty + i * 16;
    int s = s0 + sl;
    if (s < nsrc) xT[(size_t)s * 64 + tx] = tile[sl][tx];
  }
}

// ---------- atomic SpMM: one wave per 256-edge chunk ----------
__global__ __launch_bounds__(256) void spmm_atomic_kernel(
    const int* __restrict__ row, const int* __restrict__ col,
    const float* __restrict__ vals, const float* __restrict__ xT,
    float* __restrict__ accT, int nnz) {
  const int lane = threadIdx.x & 63;
  const int wslot = __builtin_amdgcn_readfirstlane(threadIdx.x >> 6);
  const int wavesPerBlk = blockDim.x >> 6;
  const int wid = blockIdx.x * wavesPerBlk + wslot;
  const int W = gridDim.x * wavesPerBlk;
  const int nch = (nnz + 255) >> 8;
  for (int ch = wid; ch < nch; ch += W) {
    const int e0 = ch << 8;
    const int eend = (e0 + 256 < nnz) ? e0 + 256 : nnz;
#pragma unroll 4
    for (int e = e0; e < eend; ++e) {
      // e is wave-uniform -> row/col/vals land as scalar (broadcast) loads
      const int r = row[e];
      const int c = col[e];
      const float v = vals[e];
      const float xv = xT[((size_t)c << 6) + lane];
      unsafeAtomicAdd(&accT[((size_t)r << 6) + lane], v * xv);
    }
  }
}

// ---------- accT (ndst, 64) + bias -> out (64, ndst) ----------
__global__ __launch_bounds__(1024) void write_out_kernel(
    const float* __restrict__ accT, const float* __restrict__ bias,
    float* __restrict__ out, int ndst) {
  __shared__ float tile[64][65];
  int d0 = blockIdx.x * 64;
  int tx = threadIdx.x;
  int ty = threadIdx.y;
#pragma unroll
  for (int i = 0; i < 4; ++i) {
    int dl = ty + i * 16;
    int d = d0 + dl;
    tile[tx][dl] = (d < ndst) ? accT[(size_t)d * 64 + tx] : 0.f;  // tx = b
  }
  __syncthreads();
#pragma unroll
  for (int i = 0; i < 4; ++i) {
    int b = ty + i * 16;
    int d = d0 + tx;
    if (d < ndst) out[(size_t)b * ndst + d] = tile[b][tx] + bias[d];
  }
}

extern "C" void kernel_launch(void* const* d_in, const int* in_sizes, int n_in,
                              void* d_out, int out_size, void* d_ws, size_t ws_size,
                              hipStream_t stream) {
  const float* x = (const float*)d_in[0];
  const float* vals = (const float*)d_in[1];
  const float* bias = (const float*)d_in[2];
  const int* row = (const int*)d_in[3];
  const int* col = (const int*)d_in[4];
  float* out = (float*)d_out;

  const int nnz = in_sizes[1];
  const int ndst = in_sizes[2];
  const int B = out_size / ndst;  // == 64 for this problem
  const int nsrc = in_sizes[0] / B;

  // workspace layout (256B-aligned chunks)
  size_t off = 0;
  auto take = [&](size_t bytes) {
    void* p = (char*)d_ws + off;
    off += (bytes + 255) & ~(size_t)255;
    return p;
  };
  float* xT = (float*)take((size_t)nsrc * 64 * 4);
  float* accT = (float*)take((size_t)ndst * 64 * 4);
  (void)ws_size;

  // accT must be zeroed every call (graph replays don't re-poison)
  hipMemsetAsync(accT, 0, (size_t)ndst * 64 * 4, stream);

  // 1. transpose x -> xT
  {
    dim3 blk(64, 16);
    int grid = (nsrc + 63) / 64;
    transpose_x_kernel<<<grid, blk, 0, stream>>>(x, xT, nsrc);
  }
  // 2. atomic SpMM over edges (one wave per 256-edge chunk)
  {
    int wavesPerBlk = 256 / 64;
    int nch = (nnz + 255) / 256;
    int grid = (nch + wavesPerBlk - 1) / wavesPerBlk;
    spmm_atomic_kernel<<<grid, 256, 0, stream>>>(row, col, vals, xT, accT, nnz);
  }
  // 3. transpose + bias -> out
  {
    dim3 blk(64, 16);
    int grid = (ndst + 63) / 64;
    write_out_kernel<<<grid, blk, 0, stream>>>(accT, bias, out, ndst);
  }
}